// Round 5
// baseline (812.088 us; speedup 1.0000x reference)
//
#include <hip/hip_runtime.h>
#include <math.h>

#define H 300
#define BB 64
#define TT 512
#define VV 50257
#define KC 30

// ---------- transpose 300x300: out[r][c] = in[c][r] (U only) ----------
__global__ void transpose_k(const float* __restrict__ in, float* __restrict__ out) {
    int idx = blockIdx.x * blockDim.x + threadIdx.x;
    if (idx < H * H) {
        int r = idx / H, c = idx - r * H;
        out[idx] = in[c * H + r];
    }
}

// ---------- ux[t][b][g] = sum_h emb[tok[b][t]][h] * U[g][h] ----------
__global__ __launch_bounds__(256) void ux_k(const int* __restrict__ tokens,
                                            const float* __restrict__ emb,
                                            const float* __restrict__ Ut,   // Ut[h][g] = U[g][h]
                                            float* __restrict__ ux) {
    __shared__ __align__(16) float x_s[KC][BB];
    __shared__ __align__(16) float ut_s[KC][304];
    __shared__ int tok_s[BB];

    const int t = blockIdx.x;
    const int tid = threadIdx.x;
    if (tid < BB) tok_s[tid] = tokens[tid * TT + t];

    const int tb = tid >> 4;
    const int tg = tid & 15;
    const int b0 = tb * 4;
    const int g0 = tg * 20;
    const bool active = (tg < 15);

    float acc[4][20];
#pragma unroll
    for (int i = 0; i < 4; ++i)
#pragma unroll
        for (int j = 0; j < 20; ++j) acc[i][j] = 0.f;

    __syncthreads();

    for (int h0 = 0; h0 < H; h0 += KC) {
        for (int i = tid; i < BB * 32; i += 256) {
            int b = i >> 5, k = i & 31;
            if (k < KC) x_s[k][b] = emb[tok_s[b] * H + h0 + k];
        }
        for (int i = tid; i < KC * H; i += 256) {
            int k = i / H, g = i - k * H;
            ut_s[k][g] = Ut[(h0 + k) * H + g];
        }
        __syncthreads();
        if (active) {
#pragma unroll 2
            for (int k = 0; k < KC; ++k) {
                float4 xa = *reinterpret_cast<const float4*>(&x_s[k][b0]);
                float4 u0 = *reinterpret_cast<const float4*>(&ut_s[k][g0 + 0]);
                float4 u1 = *reinterpret_cast<const float4*>(&ut_s[k][g0 + 4]);
                float4 u2 = *reinterpret_cast<const float4*>(&ut_s[k][g0 + 8]);
                float4 u3 = *reinterpret_cast<const float4*>(&ut_s[k][g0 + 12]);
                float4 u4 = *reinterpret_cast<const float4*>(&ut_s[k][g0 + 16]);
                const float xr[4] = {xa.x, xa.y, xa.z, xa.w};
                const float ur[20] = {u0.x, u0.y, u0.z, u0.w,
                                      u1.x, u1.y, u1.z, u1.w,
                                      u2.x, u2.y, u2.z, u2.w,
                                      u3.x, u3.y, u3.z, u3.w,
                                      u4.x, u4.y, u4.z, u4.w};
#pragma unroll
                for (int i = 0; i < 4; ++i)
#pragma unroll
                    for (int j = 0; j < 20; ++j)
                        acc[i][j] += xr[i] * ur[j];
            }
        }
        __syncthreads();
    }

    if (active) {
#pragma unroll
        for (int i = 0; i < 4; ++i) {
            float* dst = ux + (t * BB + b0 + i) * H + g0;
#pragma unroll
            for (int jq = 0; jq < 5; ++jq) {
                *reinterpret_cast<float4*>(dst + jq * 4) =
                    make_float4(acc[i][jq * 4 + 0], acc[i][jq * 4 + 1],
                                acc[i][jq * 4 + 2], acc[i][jq * 4 + 3]);
            }
        }
    }
}

// ---------- recurrence: one block per batch, 512 threads (8 waves) ----------
// v6: R3 taught: gfx950 VALU cannot read AGPRs as operands (storage-only;
// v_accvgpr_read per element per use). R1/R2 issue accounting: the allocator
// splits the unified RF ~evenly and parks W in AGPRs -> ~200 copy-issues per
// wave per step. R4 taught: "+v" pins on float4 fail ("tied indirect register
// inputs"); SCALAR "+v" pins are supported. So v6 holds W as 180 scalar
// floats (loaded via float4, unpacked) and pins all 180 each iteration with
// 9 asm statements x 20 scalar operands -> arch residence is the cheapest
// legal allocation (AGPR-parking would cost 180 copies AND the arch regs).
// Capacity: 180 W + ~45 working <= 256 arch @ waves_per_eu(2,2);
// 2 waves/SIMD x 256 = 512 of 2048-reg file. LDS 83.2KB -> 1 block/CU.
// Decomposition (same FP order as R1/R2 -> bit-identical): 500 workers =
// (c in [0,5)) x (g3 in [0,100)); rows {g3,g3+100,g3+200}, cols
// [c*60,c*60+60). 300-lane combine (5 adds + tanh).
#define RNN_Q15(X) X(0) X(1) X(2) X(3) X(4) X(5) X(6) X(7) X(8) X(9) \
    X(10) X(11) X(12) X(13) X(14)

__global__ __attribute__((amdgpu_flat_work_group_size(512, 512), amdgpu_waves_per_eu(2, 2)))
void rnn_k(const float* __restrict__ W,     // W[g][h] read directly
           const float* __restrict__ ux,    // [T][B][H]
           const float* __restrict__ ihs,
           float* __restrict__ hlast) {
    __shared__ __align__(16) float shpool[20800];   // 83,200 B -> 1 block/CU
    float* h_s = shpool;            // [0,304)    current hidden state
    float* p_s = shpool + 304;      // [304,1824) partials p_s[c][304]

    const int b = blockIdx.x;
    const int tid = threadIdx.x;
    const int tt = (tid < 500) ? tid : 499;  // tail lanes duplicate; writes guarded
    const int c  = tt / 100;                 // col chunk 0..4
    const int g3 = tt - c * 100;             // row-group 0..99

    const float4* w0p = reinterpret_cast<const float4*>(W + (size_t)(g3      ) * H + c * 60);
    const float4* w1p = reinterpret_cast<const float4*>(W + (size_t)(g3 + 100) * H + c * 60);
    const float4* w2p = reinterpret_cast<const float4*>(W + (size_t)(g3 + 200) * H + c * 60);

    // Load W as float4 (coalesced), unpack to 180 scalars (pinnable).
#define RNN_DW(q) \
    float4 t0_##q = w0p[q]; \
    float w0_##q##_x = t0_##q.x, w0_##q##_y = t0_##q.y, \
          w0_##q##_z = t0_##q.z, w0_##q##_w = t0_##q.w; \
    float4 t1_##q = w1p[q]; \
    float w1_##q##_x = t1_##q.x, w1_##q##_y = t1_##q.y, \
          w1_##q##_z = t1_##q.z, w1_##q##_w = t1_##q.w; \
    float4 t2_##q = w2p[q]; \
    float w2_##q##_x = t2_##q.x, w2_##q##_y = t2_##q.y, \
          w2_##q##_z = t2_##q.z, w2_##q##_w = t2_##q.w;
    RNN_Q15(RNN_DW)
#undef RNN_DW

    if (tid < H) h_s[tid] = ihs[b * H + tid];

    const float* uxr = ux + (size_t)b * H + tid;   // valid when tid < 300
    float u = 0.f;
    if (tid < H) u = uxr[0];                       // t = 0
    __syncthreads();

    const float4* hs4 = reinterpret_cast<const float4*>(h_s);
    const int c15 = c * 15;

#define PINQ(r, q) "+v"(w##r##_##q##_x), "+v"(w##r##_##q##_y), \
                   "+v"(w##r##_##q##_z), "+v"(w##r##_##q##_w)

#pragma unroll 1
    for (int t = 0; t < TT; ++t) {
        // Pin all 180 W scalars to ARCH VGPRs each iteration (zero insts).
        asm volatile("" : PINQ(0, 0), PINQ(0, 1), PINQ(0, 2), PINQ(0, 3), PINQ(0, 4));
        asm volatile("" : PINQ(0, 5), PINQ(0, 6), PINQ(0, 7), PINQ(0, 8), PINQ(0, 9));
        asm volatile("" : PINQ(0, 10), PINQ(0, 11), PINQ(0, 12), PINQ(0, 13), PINQ(0, 14));
        asm volatile("" : PINQ(1, 0), PINQ(1, 1), PINQ(1, 2), PINQ(1, 3), PINQ(1, 4));
        asm volatile("" : PINQ(1, 5), PINQ(1, 6), PINQ(1, 7), PINQ(1, 8), PINQ(1, 9));
        asm volatile("" : PINQ(1, 10), PINQ(1, 11), PINQ(1, 12), PINQ(1, 13), PINQ(1, 14));
        asm volatile("" : PINQ(2, 0), PINQ(2, 1), PINQ(2, 2), PINQ(2, 3), PINQ(2, 4));
        asm volatile("" : PINQ(2, 5), PINQ(2, 6), PINQ(2, 7), PINQ(2, 8), PINQ(2, 9));
        asm volatile("" : PINQ(2, 10), PINQ(2, 11), PINQ(2, 12), PINQ(2, 13), PINQ(2, 14));
        float n = 0.f;
        if (tid < H && t + 1 < TT)                 // prefetch t+1 under the FMAs
            n = uxr[(size_t)(t + 1) * (BB * H)];
        float4 a0 = make_float4(0.f, 0.f, 0.f, 0.f);
        float4 a1 = make_float4(0.f, 0.f, 0.f, 0.f);
        float4 a2 = make_float4(0.f, 0.f, 0.f, 0.f);
#define RNN_FMA(q) { float4 h4 = hs4[c15 + q]; \
        a0.x += w0_##q##_x * h4.x; a0.y += w0_##q##_y * h4.y; \
        a0.z += w0_##q##_z * h4.z; a0.w += w0_##q##_w * h4.w; \
        a1.x += w1_##q##_x * h4.x; a1.y += w1_##q##_y * h4.y; \
        a1.z += w1_##q##_z * h4.z; a1.w += w1_##q##_w * h4.w; \
        a2.x += w2_##q##_x * h4.x; a2.y += w2_##q##_y * h4.y; \
        a2.z += w2_##q##_z * h4.z; a2.w += w2_##q##_w * h4.w; }
        RNN_Q15(RNN_FMA)
#undef RNN_FMA
        float pA0 = (a0.x + a0.y) + (a0.z + a0.w);
        float pA1 = (a1.x + a1.y) + (a1.z + a1.w);
        float pA2 = (a2.x + a2.y) + (a2.z + a2.w);
        if (tid < 500) {                           // stride-1, conflict-free
            p_s[c * 304 + g3      ] = pA0;
            p_s[c * 304 + g3 + 100] = pA1;
            p_s[c * 304 + g3 + 200] = pA2;
        }
        __syncthreads();                           // barrier #1
        if (tid < H) {                             // 300 combiners, 1 row each
            float z = p_s[tid] + u;                // ((((c0+u)+c1)+c2)+c3)+c4
            z += p_s[304 + tid];
            z += p_s[608 + tid];
            z += p_s[912 + tid];
            z += p_s[1216 + tid];
            float e = __expf(2.f * z);
            h_s[tid] = 1.f - 2.f * __builtin_amdgcn_rcpf(e + 1.f);
        }
        u = n;
        __syncthreads();                           // barrier #2
    }
#undef PINQ
    if (tid < H) hlast[b * H + tid] = h_s[tid];
}

// ---------- logits: tiled GEMM  C[64,50257] = h[64,300] . Wout^T ----------
// Block tile [64 b x 128 v], 256 threads, micro-tile 8b x 4v per thread.
// h-chunks of 32 staged in LDS; Wout staged transposed (coalesced global
// reads, every byte read once -> 60 MB total at HBM rate).
__global__ __launch_bounds__(256) void logits_k(const float* __restrict__ hlast,
                                                const float* __restrict__ Wout,
                                                const float* __restrict__ bout,
                                                float* __restrict__ out) {
    __shared__ __align__(16) float Ws[32 * 132];   // Ws[h'][v'], stride 132
    __shared__ __align__(16) float hs[32 * 76];    // hs[h'][b],  stride 76
    const int tid = threadIdx.x;
    const int tv = tid & 31;          // v' = tv*4
    const int tb = tid >> 5;          // b0 = tb*8
    const int v0 = blockIdx.x * 128;

    float acc[8][4];
#pragma unroll
    for (int i = 0; i < 8; ++i)
#pragma unroll
        for (int j = 0; j < 4; ++j) acc[i][j] = 0.f;

    for (int hb = 0; hb < H; hb += 32) {
        __syncthreads();
        {   // stage Wout tile transposed: thread -> (v'=tid>>1, half q=tid&1)
            const int vp = tid >> 1;
            const int hloc = (tid & 1) * 16;
            int vv = v0 + vp; if (vv > VV - 1) vv = VV - 1;
            const float* wrow = Wout + (size_t)vv * H + hb + hloc;
#pragma unroll
            for (int i = 0; i < 4; ++i) {
                const int hg = hb + hloc + i * 4;
                float4 val;
                if (hg + 3 < H) {
                    val = *reinterpret_cast<const float4*>(wrow + i * 4);
                } else {
                    val.x = (hg + 0 < H) ? wrow[i * 4 + 0] : 0.f;
                    val.y = (hg + 1 < H) ? wrow[i * 4 + 1] : 0.f;
                    val.z = (hg + 2 < H) ? wrow[i * 4 + 2] : 0.f;
                    val.w = (hg + 3 < H) ? wrow[i * 4 + 3] : 0.f;
                }
                Ws[(hloc + i * 4 + 0) * 132 + vp] = val.x;
                Ws[(hloc + i * 4 + 1) * 132 + vp] = val.y;
                Ws[(hloc + i * 4 + 2) * 132 + vp] = val.z;
                Ws[(hloc + i * 4 + 3) * 132 + vp] = val.w;
            }
        }
        {   // stage h tile transposed: thread -> (b=tid>>2, 8 h's)
            const int bb = tid >> 2;
            const int hl = (tid & 3) * 8;
            const float* hrow = hlast + bb * H + hb + hl;
#pragma unroll
            for (int i = 0; i < 2; ++i) {
                const int hg = hb + hl + i * 4;
                float4 val;
                if (hg + 3 < H) {
                    val = *reinterpret_cast<const float4*>(hrow + i * 4);
                } else {
                    val.x = (hg + 0 < H) ? hrow[i * 4 + 0] : 0.f;
                    val.y = (hg + 1 < H) ? hrow[i * 4 + 1] : 0.f;
                    val.z = (hg + 2 < H) ? hrow[i * 4 + 2] : 0.f;
                    val.w = (hg + 3 < H) ? hrow[i * 4 + 3] : 0.f;
                }
                hs[(hl + i * 4 + 0) * 76 + bb] = val.x;
                hs[(hl + i * 4 + 1) * 76 + bb] = val.y;
                hs[(hl + i * 4 + 2) * 76 + bb] = val.z;
                hs[(hl + i * 4 + 3) * 76 + bb] = val.w;
            }
        }
        __syncthreads();
        const float4* Ws4 = reinterpret_cast<const float4*>(Ws);  // stride 33
        const float4* hs4 = reinterpret_cast<const float4*>(hs);  // stride 19
#pragma unroll
        for (int h2 = 0; h2 < 32; ++h2) {
            float4 w4  = Ws4[h2 * 33 + tv];
            float4 h4a = hs4[h2 * 19 + tb * 2];
            float4 h4b = hs4[h2 * 19 + tb * 2 + 1];
            const float hv[8] = {h4a.x, h4a.y, h4a.z, h4a.w,
                                 h4b.x, h4b.y, h4b.z, h4b.w};
#pragma unroll
            for (int bi = 0; bi < 8; ++bi) {
                acc[bi][0] += hv[bi] * w4.x;
                acc[bi][1] += hv[bi] * w4.y;
                acc[bi][2] += hv[bi] * w4.z;
                acc[bi][3] += hv[bi] * w4.w;
            }
        }
    }

    const int vg = v0 + tv * 4;
    float4 bq;
    if (vg + 3 < VV) bq = *reinterpret_cast<const float4*>(bout + vg);
    else {
        bq.x = (vg + 0 < VV) ? bout[vg + 0] : 0.f;
        bq.y = (vg + 1 < VV) ? bout[vg + 1] : 0.f;
        bq.z = (vg + 2 < VV) ? bout[vg + 2] : 0.f;
        bq.w = (vg + 3 < VV) ? bout[vg + 3] : 0.f;
    }
#pragma unroll
    for (int bi = 0; bi < 8; ++bi) {
        const int bb = tb * 8 + bi;
        float* op = out + (size_t)bb * VV + vg;   // VV odd -> rows not 16B-aligned: scalar stores
        if (vg + 0 < VV) op[0] = acc[bi][0] + bq.x;
        if (vg + 1 < VV) op[1] = acc[bi][1] + bq.y;
        if (vg + 2 < VV) op[2] = acc[bi][2] + bq.z;
        if (vg + 3 < VV) op[3] = acc[bi][3] + bq.w;
    }
}

extern "C" void kernel_launch(void* const* d_in, const int* in_sizes, int n_in,
                              void* d_out, int out_size, void* d_ws, size_t ws_size,
                              hipStream_t stream) {
    const float* ihs    = (const float*)d_in[0];
    const int*   tokens = (const int*)  d_in[1];
    const float* emb    = (const float*)d_in[2];
    const float* W      = (const float*)d_in[3];
    const float* U      = (const float*)d_in[4];
    const float* Wout   = (const float*)d_in[5];
    const float* bout   = (const float*)d_in[6];
    float* out = (float*)d_out;

    char* ws = (char*)d_ws;
    float* Ut    = (float*)(ws + 0);          // 360,000 B
    float* hlast = (float*)(ws + 400000);     // 76,800 B
    float* ux    = (float*)(ws + 1048576);    // 39,321,600 B  [T][B][H]

    const int tp_blocks = (H * H + 255) / 256;
    transpose_k<<<tp_blocks, 256, 0, stream>>>(U, Ut);
    ux_k<<<TT, 256, 0, stream>>>(tokens, emb, Ut, ux);
    rnn_k<<<BB, 512, 0, stream>>>(W, ux, ihs, hlast);
    logits_k<<<(VV + 127) / 128, 256, 0, stream>>>(hlast, Wout, bout, out);
}

// Round 6
// 750.273 us; speedup vs baseline: 1.0824x; 1.0824x over previous
//
#include <hip/hip_runtime.h>
#include <math.h>

#define H 300
#define BB 64
#define TT 512
#define VV 50257
#define KC 30

typedef float v2f __attribute__((ext_vector_type(2)));

// ---------- transpose 300x300: out[r][c] = in[c][r] (U only) ----------
__global__ void transpose_k(const float* __restrict__ in, float* __restrict__ out) {
    int idx = blockIdx.x * blockDim.x + threadIdx.x;
    if (idx < H * H) {
        int r = idx / H, c = idx - r * H;
        out[idx] = in[c * H + r];
    }
}

// ---------- ux[t][b][g] = sum_h emb[tok[b][t]][h] * U[g][h] ----------
__global__ __launch_bounds__(256) void ux_k(const int* __restrict__ tokens,
                                            const float* __restrict__ emb,
                                            const float* __restrict__ Ut,   // Ut[h][g] = U[g][h]
                                            float* __restrict__ ux) {
    __shared__ __align__(16) float x_s[KC][BB];
    __shared__ __align__(16) float ut_s[KC][304];
    __shared__ int tok_s[BB];

    const int t = blockIdx.x;
    const int tid = threadIdx.x;
    if (tid < BB) tok_s[tid] = tokens[tid * TT + t];

    const int tb = tid >> 4;
    const int tg = tid & 15;
    const int b0 = tb * 4;
    const int g0 = tg * 20;
    const bool active = (tg < 15);

    float acc[4][20];
#pragma unroll
    for (int i = 0; i < 4; ++i)
#pragma unroll
        for (int j = 0; j < 20; ++j) acc[i][j] = 0.f;

    __syncthreads();

    for (int h0 = 0; h0 < H; h0 += KC) {
        for (int i = tid; i < BB * 32; i += 256) {
            int b = i >> 5, k = i & 31;
            if (k < KC) x_s[k][b] = emb[tok_s[b] * H + h0 + k];
        }
        for (int i = tid; i < KC * H; i += 256) {
            int k = i / H, g = i - k * H;
            ut_s[k][g] = Ut[(h0 + k) * H + g];
        }
        __syncthreads();
        if (active) {
#pragma unroll 2
            for (int k = 0; k < KC; ++k) {
                float4 xa = *reinterpret_cast<const float4*>(&x_s[k][b0]);
                float4 u0 = *reinterpret_cast<const float4*>(&ut_s[k][g0 + 0]);
                float4 u1 = *reinterpret_cast<const float4*>(&ut_s[k][g0 + 4]);
                float4 u2 = *reinterpret_cast<const float4*>(&ut_s[k][g0 + 8]);
                float4 u3 = *reinterpret_cast<const float4*>(&ut_s[k][g0 + 12]);
                float4 u4 = *reinterpret_cast<const float4*>(&ut_s[k][g0 + 16]);
                const float xr[4] = {xa.x, xa.y, xa.z, xa.w};
                const float ur[20] = {u0.x, u0.y, u0.z, u0.w,
                                      u1.x, u1.y, u1.z, u1.w,
                                      u2.x, u2.y, u2.z, u2.w,
                                      u3.x, u3.y, u3.z, u3.w,
                                      u4.x, u4.y, u4.z, u4.w};
#pragma unroll
                for (int i = 0; i < 4; ++i)
#pragma unroll
                    for (int j = 0; j < 20; ++j)
                        acc[i][j] += xr[i] * ur[j];
            }
        }
        __syncthreads();
    }

    if (active) {
#pragma unroll
        for (int i = 0; i < 4; ++i) {
            float* dst = ux + (t * BB + b0 + i) * H + g0;
#pragma unroll
            for (int jq = 0; jq < 5; ++jq) {
                *reinterpret_cast<float4*>(dst + jq * 4) =
                    make_float4(acc[i][jq * 4 + 0], acc[i][jq * 4 + 1],
                                acc[i][jq * 4 + 2], acc[i][jq * 4 + 3]);
            }
        }
    }
}

// ---------- recurrence: one block per batch, 512 threads (8 waves) ----------
// v7 = v2 (the measured-best 413us structure) with the inner product
// converted to v_pk_fma_f32 (2 f32 FMAs/inst; MI355X's 157 TF fp32 rate IS
// the packed rate — scalar v_fma is half, m07). Cross-round accounting
// (R0/R1/R2/R5): VALU busy/SIMD/step is ~1600-1750cy in every decomposition,
// vs ~860cy of real work; the excess is one v_accvgpr_read per W element per
// step (allocator parks W in AGPRs; arch grant ~budget/2 at every occupancy;
// R3: VALU cannot read AGPRs directly; R4/R5: pinning fails/regresses). pk
// halves the REAL-work term: 180 fmac -> 90 pk-insts, issue/wave/step
// ~395 -> ~305. Accumulator pairs {x,y},{z,w} and reduce (x+y)+(z+w) keep
// FP order bit-identical to v2.
// Decomposition: 500 workers = (c in [0,5)) x (g3 in [0,100)); rows
// {g3,g3+100,g3+200}, cols [c*60,c*60+60) = 15 quads = 30 pk-pairs/row.
// 100-lane combine (3 rows each). LDS 83.2KB -> 1 block/CU.
#define RNN_Q15(X) X(0) X(1) X(2) X(3) X(4) X(5) X(6) X(7) X(8) X(9) \
    X(10) X(11) X(12) X(13) X(14)

__global__ __attribute__((amdgpu_flat_work_group_size(512, 512), amdgpu_waves_per_eu(2, 2)))
void rnn_k(const float* __restrict__ W,     // W[g][h] read directly
           const float* __restrict__ ux,    // [T][B][H]
           const float* __restrict__ ihs,
           float* __restrict__ hlast) {
    __shared__ __align__(16) float shpool[20800];   // 83,200 B -> 1 block/CU
    float* h_s = shpool;            // [0,304)    current hidden state
    float* p_s = shpool + 304;      // [304,1824) partials p_s[c-1][304], c=1..4

    const int b = blockIdx.x;
    const int tid = threadIdx.x;
    const int tt = (tid < 500) ? tid : 499;  // tail lanes duplicate; writes guarded
    const int c  = tt / 100;                 // col chunk 0..4
    const int g3 = tt - c * 100;             // row-group 0..99

    const float4* w0p = reinterpret_cast<const float4*>(W + (size_t)(g3      ) * H + c * 60);
    const float4* w1p = reinterpret_cast<const float4*>(W + (size_t)(g3 + 100) * H + c * 60);
    const float4* w2p = reinterpret_cast<const float4*>(W + (size_t)(g3 + 200) * H + c * 60);

    // Load W as float4 (coalesced), hold as v2f pairs (pk_fma operands).
#define RNN_DW(q) \
    float4 t0_##q = w0p[q]; \
    v2f w0l_##q = {t0_##q.x, t0_##q.y}; v2f w0h_##q = {t0_##q.z, t0_##q.w}; \
    float4 t1_##q = w1p[q]; \
    v2f w1l_##q = {t1_##q.x, t1_##q.y}; v2f w1h_##q = {t1_##q.z, t1_##q.w}; \
    float4 t2_##q = w2p[q]; \
    v2f w2l_##q = {t2_##q.x, t2_##q.y}; v2f w2h_##q = {t2_##q.z, t2_##q.w};
    RNN_Q15(RNN_DW)
#undef RNN_DW

    if (tid < H) h_s[tid] = ihs[b * H + tid];

    const float* uxb = ux + (size_t)b * H;
    float u0 = 0.f, u1 = 0.f, u2 = 0.f;
    if (tid < 100) {                          // prefetch t=0 (combiners only)
        u0 = uxb[g3];
        u1 = uxb[100 + g3];
        u2 = uxb[200 + g3];
    }
    __syncthreads();

    const float4* hs4 = reinterpret_cast<const float4*>(h_s);
    const int c15 = c * 15;

#pragma unroll 1
    for (int t = 0; t < TT; ++t) {
        float n0 = 0.f, n1 = 0.f, n2 = 0.f;
        if (tid < 100 && t + 1 < TT) {        // prefetch t+1 under the FMAs
            const float* nx = uxb + (size_t)(t + 1) * (BB * H);
            n0 = nx[g3];
            n1 = nx[100 + g3];
            n2 = nx[200 + g3];
        }
        v2f a0l = {0.f, 0.f}, a0h = {0.f, 0.f};
        v2f a1l = {0.f, 0.f}, a1h = {0.f, 0.f};
        v2f a2l = {0.f, 0.f}, a2h = {0.f, 0.f};
#define RNN_FMA(q) { float4 h4 = hs4[c15 + q]; \
        v2f hl = {h4.x, h4.y}; v2f hh = {h4.z, h4.w}; \
        a0l = __builtin_elementwise_fma(w0l_##q, hl, a0l); \
        a0h = __builtin_elementwise_fma(w0h_##q, hh, a0h); \
        a1l = __builtin_elementwise_fma(w1l_##q, hl, a1l); \
        a1h = __builtin_elementwise_fma(w1h_##q, hh, a1h); \
        a2l = __builtin_elementwise_fma(w2l_##q, hl, a2l); \
        a2h = __builtin_elementwise_fma(w2h_##q, hh, a2h); }
        RNN_Q15(RNN_FMA)
#undef RNN_FMA
        float pA0 = (a0l.x + a0l.y) + (a0h.x + a0h.y);
        float pA1 = (a1l.x + a1l.y) + (a1h.x + a1h.y);
        float pA2 = (a2l.x + a2l.y) + (a2h.x + a2h.y);
        if (tid < 500 && c != 0) {            // stride-1 stores, conflict-free
            p_s[(c - 1) * 304 + g3      ] = pA0;
            p_s[(c - 1) * 304 + g3 + 100] = pA1;
            p_s[(c - 1) * 304 + g3 + 200] = pA2;
        }
        __syncthreads();                      // barrier #1
        if (tid < 100) {                      // c==0 workers combine their 3 rows
            float z0 = pA0 + u0;
            float z1 = pA1 + u1;
            float z2 = pA2 + u2;
#pragma unroll
            for (int j = 0; j < 4; ++j) {
                z0 += p_s[j * 304 + g3];
                z1 += p_s[j * 304 + g3 + 100];
                z2 += p_s[j * 304 + g3 + 200];
            }
            float e0 = __expf(2.f * z0);
            float e1 = __expf(2.f * z1);
            float e2 = __expf(2.f * z2);
            h_s[g3      ] = 1.f - 2.f * __builtin_amdgcn_rcpf(e0 + 1.f);
            h_s[g3 + 100] = 1.f - 2.f * __builtin_amdgcn_rcpf(e1 + 1.f);
            h_s[g3 + 200] = 1.f - 2.f * __builtin_amdgcn_rcpf(e2 + 1.f);
        }
        u0 = n0; u1 = n1; u2 = n2;
        __syncthreads();                      // barrier #2
    }
    if (tid < H) hlast[b * H + tid] = h_s[tid];
}

// ---------- logits: tiled GEMM  C[64,50257] = h[64,300] . Wout^T ----------
// Block tile [64 b x 128 v], 256 threads, micro-tile 8b x 4v per thread.
// h-chunks of 32 staged in LDS; Wout staged transposed (coalesced global
// reads, every byte read once -> 60 MB total at HBM rate).
__global__ __launch_bounds__(256) void logits_k(const float* __restrict__ hlast,
                                                const float* __restrict__ Wout,
                                                const float* __restrict__ bout,
                                                float* __restrict__ out) {
    __shared__ __align__(16) float Ws[32 * 132];   // Ws[h'][v'], stride 132
    __shared__ __align__(16) float hs[32 * 76];    // hs[h'][b],  stride 76
    const int tid = threadIdx.x;
    const int tv = tid & 31;          // v' = tv*4
    const int tb = tid >> 5;          // b0 = tb*8
    const int v0 = blockIdx.x * 128;

    float acc[8][4];
#pragma unroll
    for (int i = 0; i < 8; ++i)
#pragma unroll
        for (int j = 0; j < 4; ++j) acc[i][j] = 0.f;

    for (int hb = 0; hb < H; hb += 32) {
        __syncthreads();
        {   // stage Wout tile transposed: thread -> (v'=tid>>1, half q=tid&1)
            const int vp = tid >> 1;
            const int hloc = (tid & 1) * 16;
            int vv = v0 + vp; if (vv > VV - 1) vv = VV - 1;
            const float* wrow = Wout + (size_t)vv * H + hb + hloc;
#pragma unroll
            for (int i = 0; i < 4; ++i) {
                const int hg = hb + hloc + i * 4;
                float4 val;
                if (hg + 3 < H) {
                    val = *reinterpret_cast<const float4*>(wrow + i * 4);
                } else {
                    val.x = (hg + 0 < H) ? wrow[i * 4 + 0] : 0.f;
                    val.y = (hg + 1 < H) ? wrow[i * 4 + 1] : 0.f;
                    val.z = (hg + 2 < H) ? wrow[i * 4 + 2] : 0.f;
                    val.w = (hg + 3 < H) ? wrow[i * 4 + 3] : 0.f;
                }
                Ws[(hloc + i * 4 + 0) * 132 + vp] = val.x;
                Ws[(hloc + i * 4 + 1) * 132 + vp] = val.y;
                Ws[(hloc + i * 4 + 2) * 132 + vp] = val.z;
                Ws[(hloc + i * 4 + 3) * 132 + vp] = val.w;
            }
        }
        {   // stage h tile transposed: thread -> (b=tid>>2, 8 h's)
            const int bb = tid >> 2;
            const int hl = (tid & 3) * 8;
            const float* hrow = hlast + bb * H + hb + hl;
#pragma unroll
            for (int i = 0; i < 2; ++i) {
                const int hg = hb + hl + i * 4;
                float4 val;
                if (hg + 3 < H) {
                    val = *reinterpret_cast<const float4*>(hrow + i * 4);
                } else {
                    val.x = (hg + 0 < H) ? hrow[i * 4 + 0] : 0.f;
                    val.y = (hg + 1 < H) ? hrow[i * 4 + 1] : 0.f;
                    val.z = (hg + 2 < H) ? hrow[i * 4 + 2] : 0.f;
                    val.w = (hg + 3 < H) ? hrow[i * 4 + 3] : 0.f;
                }
                hs[(hl + i * 4 + 0) * 76 + bb] = val.x;
                hs[(hl + i * 4 + 1) * 76 + bb] = val.y;
                hs[(hl + i * 4 + 2) * 76 + bb] = val.z;
                hs[(hl + i * 4 + 3) * 76 + bb] = val.w;
            }
        }
        __syncthreads();
        const float4* Ws4 = reinterpret_cast<const float4*>(Ws);  // stride 33
        const float4* hs4 = reinterpret_cast<const float4*>(hs);  // stride 19
#pragma unroll
        for (int h2 = 0; h2 < 32; ++h2) {
            float4 w4  = Ws4[h2 * 33 + tv];
            float4 h4a = hs4[h2 * 19 + tb * 2];
            float4 h4b = hs4[h2 * 19 + tb * 2 + 1];
            const float hv[8] = {h4a.x, h4a.y, h4a.z, h4a.w,
                                 h4b.x, h4b.y, h4b.z, h4b.w};
#pragma unroll
            for (int bi = 0; bi < 8; ++bi) {
                acc[bi][0] += hv[bi] * w4.x;
                acc[bi][1] += hv[bi] * w4.y;
                acc[bi][2] += hv[bi] * w4.z;
                acc[bi][3] += hv[bi] * w4.w;
            }
        }
    }

    const int vg = v0 + tv * 4;
    float4 bq;
    if (vg + 3 < VV) bq = *reinterpret_cast<const float4*>(bout + vg);
    else {
        bq.x = (vg + 0 < VV) ? bout[vg + 0] : 0.f;
        bq.y = (vg + 1 < VV) ? bout[vg + 1] : 0.f;
        bq.z = (vg + 2 < VV) ? bout[vg + 2] : 0.f;
        bq.w = (vg + 3 < VV) ? bout[vg + 3] : 0.f;
    }
#pragma unroll
    for (int bi = 0; bi < 8; ++bi) {
        const int bb = tb * 8 + bi;
        float* op = out + (size_t)bb * VV + vg;   // VV odd -> rows not 16B-aligned: scalar stores
        if (vg + 0 < VV) op[0] = acc[bi][0] + bq.x;
        if (vg + 1 < VV) op[1] = acc[bi][1] + bq.y;
        if (vg + 2 < VV) op[2] = acc[bi][2] + bq.z;
        if (vg + 3 < VV) op[3] = acc[bi][3] + bq.w;
    }
}

extern "C" void kernel_launch(void* const* d_in, const int* in_sizes, int n_in,
                              void* d_out, int out_size, void* d_ws, size_t ws_size,
                              hipStream_t stream) {
    const float* ihs    = (const float*)d_in[0];
    const int*   tokens = (const int*)  d_in[1];
    const float* emb    = (const float*)d_in[2];
    const float* W      = (const float*)d_in[3];
    const float* U      = (const float*)d_in[4];
    const float* Wout   = (const float*)d_in[5];
    const float* bout   = (const float*)d_in[6];
    float* out = (float*)d_out;

    char* ws = (char*)d_ws;
    float* Ut    = (float*)(ws + 0);          // 360,000 B
    float* hlast = (float*)(ws + 400000);     // 76,800 B
    float* ux    = (float*)(ws + 1048576);    // 39,321,600 B  [T][B][H]

    const int tp_blocks = (H * H + 255) / 256;
    transpose_k<<<tp_blocks, 256, 0, stream>>>(U, Ut);
    ux_k<<<TT, 256, 0, stream>>>(tokens, emb, Ut, ux);
    rnn_k<<<BB, 512, 0, stream>>>(W, ux, ihs, hlast);
    logits_k<<<(VV + 127) / 128, 256, 0, stream>>>(hlast, Wout, bout, out);
}

// Round 7
// 705.835 us; speedup vs baseline: 1.1505x; 1.0630x over previous
//
#include <hip/hip_runtime.h>
#include <math.h>

#define H 300
#define BB 64
#define TT 512
#define VV 50257
#define KC 30

typedef float v2f __attribute__((ext_vector_type(2)));

// ---------- transpose 300x300: out[r][c] = in[c][r] (U only) ----------
__global__ void transpose_k(const float* __restrict__ in, float* __restrict__ out) {
    int idx = blockIdx.x * blockDim.x + threadIdx.x;
    if (idx < H * H) {
        int r = idx / H, c = idx - r * H;
        out[idx] = in[c * H + r];
    }
}

// ---------- ux[t][b][g] = sum_h emb[tok[b][t]][h] * U[g][h] ----------
// v8: inner 4x20 micro-kernel converted to v_pk_fma_f32 (R6 verified the
// builtin emits pk and halves VALU issue). Each acc element keeps its own
// FMA chain -> bit-identical output.
__global__ __launch_bounds__(256) void ux_k(const int* __restrict__ tokens,
                                            const float* __restrict__ emb,
                                            const float* __restrict__ Ut,   // Ut[h][g] = U[g][h]
                                            float* __restrict__ ux) {
    __shared__ __align__(16) float x_s[KC][BB];
    __shared__ __align__(16) float ut_s[KC][304];
    __shared__ int tok_s[BB];

    const int t = blockIdx.x;
    const int tid = threadIdx.x;
    if (tid < BB) tok_s[tid] = tokens[tid * TT + t];

    const int tb = tid >> 4;
    const int tg = tid & 15;
    const int b0 = tb * 4;
    const int g0 = tg * 20;
    const bool active = (tg < 15);

    v2f acc[4][10];
#pragma unroll
    for (int i = 0; i < 4; ++i)
#pragma unroll
        for (int j = 0; j < 10; ++j) acc[i][j] = (v2f){0.f, 0.f};

    __syncthreads();

    for (int h0 = 0; h0 < H; h0 += KC) {
        for (int i = tid; i < BB * 32; i += 256) {
            int b = i >> 5, k = i & 31;
            if (k < KC) x_s[k][b] = emb[tok_s[b] * H + h0 + k];
        }
        for (int i = tid; i < KC * H; i += 256) {
            int k = i / H, g = i - k * H;
            ut_s[k][g] = Ut[(h0 + k) * H + g];
        }
        __syncthreads();
        if (active) {
#pragma unroll 2
            for (int k = 0; k < KC; ++k) {
                float4 xa = *reinterpret_cast<const float4*>(&x_s[k][b0]);
                float4 u0 = *reinterpret_cast<const float4*>(&ut_s[k][g0 + 0]);
                float4 u1 = *reinterpret_cast<const float4*>(&ut_s[k][g0 + 4]);
                float4 u2 = *reinterpret_cast<const float4*>(&ut_s[k][g0 + 8]);
                float4 u3 = *reinterpret_cast<const float4*>(&ut_s[k][g0 + 12]);
                float4 u4 = *reinterpret_cast<const float4*>(&ut_s[k][g0 + 16]);
                const float xr[4] = {xa.x, xa.y, xa.z, xa.w};
                const v2f ur[10] = {{u0.x, u0.y}, {u0.z, u0.w},
                                    {u1.x, u1.y}, {u1.z, u1.w},
                                    {u2.x, u2.y}, {u2.z, u2.w},
                                    {u3.x, u3.y}, {u3.z, u3.w},
                                    {u4.x, u4.y}, {u4.z, u4.w}};
#pragma unroll
                for (int i = 0; i < 4; ++i) {
                    const v2f xs = {xr[i], xr[i]};
#pragma unroll
                    for (int j = 0; j < 10; ++j)
                        acc[i][j] = __builtin_elementwise_fma(xs, ur[j], acc[i][j]);
                }
            }
        }
        __syncthreads();
    }

    if (active) {
#pragma unroll
        for (int i = 0; i < 4; ++i) {
            float* dst = ux + (t * BB + b0 + i) * H + g0;
#pragma unroll
            for (int jq = 0; jq < 5; ++jq) {
                *reinterpret_cast<float4*>(dst + jq * 4) =
                    make_float4(acc[i][2 * jq].x, acc[i][2 * jq].y,
                                acc[i][2 * jq + 1].x, acc[i][2 * jq + 1].y);
            }
        }
    }
}

// ---------- recurrence: one block per batch, 768 threads (12 waves) ----------
// v8 = R2's v3 structure (3 waves/SIMD, verified 81% VALU-busy = issue-bound)
// with the inner product converted to v_pk_fma_f32 (R6-verified: halves FMA
// issue). R6 post-mortem: pk at 2 waves/SIMD exposed latency (busy 85%->44%,
// time flat) — the TLP of the 3rd wave is what lets the issue reduction
// become a time reduction. Issue/SIMD/step ~1250cy (3w x (60pk + ~110 copies
// + ovh) x 2) vs R2's measured 1608.
// Decomposition (same FP order as R1/R2/R6 -> bit-identical): 750 workers =
// (c in [0,5)) x (g2 in [0,150)); worker owns rows {g2, g2+150} over cols
// [c*60,c*60+60) = 15 quads = 30 pk pairs/row. 300-lane combine (1 row each:
// 5 adds + tanh). LDS 83.2KB > 80KB -> 1 block/CU (prevents a 2nd block from
// halving the register budget).
#define RNN_Q15(X) X(0) X(1) X(2) X(3) X(4) X(5) X(6) X(7) X(8) X(9) \
    X(10) X(11) X(12) X(13) X(14)

__global__ __attribute__((amdgpu_flat_work_group_size(768, 768), amdgpu_waves_per_eu(3, 3)))
void rnn_k(const float* __restrict__ W,     // W[g][h] read directly
           const float* __restrict__ ux,    // [T][B][H]
           const float* __restrict__ ihs,
           float* __restrict__ hlast) {
    __shared__ __align__(16) float shpool[20800];   // 83,200 B -> 1 block/CU
    float* h_s = shpool;            // [0,304)    current hidden state
    float* p_s = shpool + 304;      // [304,1824) partials p_s[c][304]

    const int b = blockIdx.x;
    const int tid = threadIdx.x;
    const int tt = (tid < 750) ? tid : 749;  // tail lanes duplicate; writes guarded
    const int c  = tt / 150;                 // col chunk 0..4
    const int g2 = tt - c * 150;             // row-pair 0..149

    const float4* w0p = reinterpret_cast<const float4*>(W + (size_t)(g2      ) * H + c * 60);
    const float4* w1p = reinterpret_cast<const float4*>(W + (size_t)(g2 + 150) * H + c * 60);

    // Load W as float4 (coalesced), hold as v2f pairs (pk_fma operands).
#define RNN_DW(q) \
    float4 t0_##q = w0p[q]; \
    v2f w0l_##q = {t0_##q.x, t0_##q.y}; v2f w0h_##q = {t0_##q.z, t0_##q.w}; \
    float4 t1_##q = w1p[q]; \
    v2f w1l_##q = {t1_##q.x, t1_##q.y}; v2f w1h_##q = {t1_##q.z, t1_##q.w};
    RNN_Q15(RNN_DW)
#undef RNN_DW

    if (tid < H) h_s[tid] = ihs[b * H + tid];

    const float* uxr = ux + (size_t)b * H + tid;   // valid when tid < 300
    float u = 0.f;
    if (tid < H) u = uxr[0];                       // t = 0
    __syncthreads();

    const float4* hs4 = reinterpret_cast<const float4*>(h_s);
    const int c15 = c * 15;

#pragma unroll 1
    for (int t = 0; t < TT; ++t) {
        float n = 0.f;
        if (tid < H && t + 1 < TT)                 // prefetch t+1 under the FMAs
            n = uxr[(size_t)(t + 1) * (BB * H)];
        v2f a0l = {0.f, 0.f}, a0h = {0.f, 0.f};
        v2f a1l = {0.f, 0.f}, a1h = {0.f, 0.f};
#define RNN_FMA(q) { float4 h4 = hs4[c15 + q]; \
        v2f hl = {h4.x, h4.y}; v2f hh = {h4.z, h4.w}; \
        a0l = __builtin_elementwise_fma(w0l_##q, hl, a0l); \
        a0h = __builtin_elementwise_fma(w0h_##q, hh, a0h); \
        a1l = __builtin_elementwise_fma(w1l_##q, hl, a1l); \
        a1h = __builtin_elementwise_fma(w1h_##q, hh, a1h); }
        RNN_Q15(RNN_FMA)
#undef RNN_FMA
        float pA = (a0l.x + a0l.y) + (a0h.x + a0h.y);
        float pB = (a1l.x + a1l.y) + (a1h.x + a1h.y);
        if (tid < 750) {                           // stride-1, conflict-free
            p_s[c * 304 + g2      ] = pA;
            p_s[c * 304 + g2 + 150] = pB;
        }
        __syncthreads();                           // barrier #1
        if (tid < H) {                             // 300 combiners, 1 row each
            float z = p_s[tid] + u;                // ((((c0+u)+c1)+c2)+c3)+c4
            z += p_s[304 + tid];
            z += p_s[608 + tid];
            z += p_s[912 + tid];
            z += p_s[1216 + tid];
            float e = __expf(2.f * z);
            h_s[tid] = 1.f - 2.f * __builtin_amdgcn_rcpf(e + 1.f);
        }
        u = n;
        __syncthreads();                           // barrier #2
    }
    if (tid < H) hlast[b * H + tid] = h_s[tid];
}

// ---------- logits: tiled GEMM  C[64,50257] = h[64,300] . Wout^T ----------
// Block tile [64 b x 128 v], 256 threads, micro-tile 8b x 4v per thread.
// h-chunks of 32 staged in LDS; Wout staged transposed (coalesced global
// reads, every byte read once -> 60 MB total at HBM rate).
__global__ __launch_bounds__(256) void logits_k(const float* __restrict__ hlast,
                                                const float* __restrict__ Wout,
                                                const float* __restrict__ bout,
                                                float* __restrict__ out) {
    __shared__ __align__(16) float Ws[32 * 132];   // Ws[h'][v'], stride 132
    __shared__ __align__(16) float hs[32 * 76];    // hs[h'][b],  stride 76
    const int tid = threadIdx.x;
    const int tv = tid & 31;          // v' = tv*4
    const int tb = tid >> 5;          // b0 = tb*8
    const int v0 = blockIdx.x * 128;

    float acc[8][4];
#pragma unroll
    for (int i = 0; i < 8; ++i)
#pragma unroll
        for (int j = 0; j < 4; ++j) acc[i][j] = 0.f;

    for (int hb = 0; hb < H; hb += 32) {
        __syncthreads();
        {   // stage Wout tile transposed: thread -> (v'=tid>>1, half q=tid&1)
            const int vp = tid >> 1;
            const int hloc = (tid & 1) * 16;
            int vv = v0 + vp; if (vv > VV - 1) vv = VV - 1;
            const float* wrow = Wout + (size_t)vv * H + hb + hloc;
#pragma unroll
            for (int i = 0; i < 4; ++i) {
                const int hg = hb + hloc + i * 4;
                float4 val;
                if (hg + 3 < H) {
                    val = *reinterpret_cast<const float4*>(wrow + i * 4);
                } else {
                    val.x = (hg + 0 < H) ? wrow[i * 4 + 0] : 0.f;
                    val.y = (hg + 1 < H) ? wrow[i * 4 + 1] : 0.f;
                    val.z = (hg + 2 < H) ? wrow[i * 4 + 2] : 0.f;
                    val.w = (hg + 3 < H) ? wrow[i * 4 + 3] : 0.f;
                }
                Ws[(hloc + i * 4 + 0) * 132 + vp] = val.x;
                Ws[(hloc + i * 4 + 1) * 132 + vp] = val.y;
                Ws[(hloc + i * 4 + 2) * 132 + vp] = val.z;
                Ws[(hloc + i * 4 + 3) * 132 + vp] = val.w;
            }
        }
        {   // stage h tile transposed: thread -> (b=tid>>2, 8 h's)
            const int bb = tid >> 2;
            const int hl = (tid & 3) * 8;
            const float* hrow = hlast + bb * H + hb + hl;
#pragma unroll
            for (int i = 0; i < 2; ++i) {
                const int hg = hb + hl + i * 4;
                float4 val;
                if (hg + 3 < H) {
                    val = *reinterpret_cast<const float4*>(hrow + i * 4);
                } else {
                    val.x = (hg + 0 < H) ? hrow[i * 4 + 0] : 0.f;
                    val.y = (hg + 1 < H) ? hrow[i * 4 + 1] : 0.f;
                    val.z = (hg + 2 < H) ? hrow[i * 4 + 2] : 0.f;
                    val.w = (hg + 3 < H) ? hrow[i * 4 + 3] : 0.f;
                }
                hs[(hl + i * 4 + 0) * 76 + bb] = val.x;
                hs[(hl + i * 4 + 1) * 76 + bb] = val.y;
                hs[(hl + i * 4 + 2) * 76 + bb] = val.z;
                hs[(hl + i * 4 + 3) * 76 + bb] = val.w;
            }
        }
        __syncthreads();
        const float4* Ws4 = reinterpret_cast<const float4*>(Ws);  // stride 33
        const float4* hs4 = reinterpret_cast<const float4*>(hs);  // stride 19
#pragma unroll
        for (int h2 = 0; h2 < 32; ++h2) {
            float4 w4  = Ws4[h2 * 33 + tv];
            float4 h4a = hs4[h2 * 19 + tb * 2];
            float4 h4b = hs4[h2 * 19 + tb * 2 + 1];
            const float hv[8] = {h4a.x, h4a.y, h4a.z, h4a.w,
                                 h4b.x, h4b.y, h4b.z, h4b.w};
#pragma unroll
            for (int bi = 0; bi < 8; ++bi) {
                acc[bi][0] += hv[bi] * w4.x;
                acc[bi][1] += hv[bi] * w4.y;
                acc[bi][2] += hv[bi] * w4.z;
                acc[bi][3] += hv[bi] * w4.w;
            }
        }
    }

    const int vg = v0 + tv * 4;
    float4 bq;
    if (vg + 3 < VV) bq = *reinterpret_cast<const float4*>(bout + vg);
    else {
        bq.x = (vg + 0 < VV) ? bout[vg + 0] : 0.f;
        bq.y = (vg + 1 < VV) ? bout[vg + 1] : 0.f;
        bq.z = (vg + 2 < VV) ? bout[vg + 2] : 0.f;
        bq.w = (vg + 3 < VV) ? bout[vg + 3] : 0.f;
    }
#pragma unroll
    for (int bi = 0; bi < 8; ++bi) {
        const int bb = tb * 8 + bi;
        float* op = out + (size_t)bb * VV + vg;   // VV odd -> rows not 16B-aligned: scalar stores
        if (vg + 0 < VV) op[0] = acc[bi][0] + bq.x;
        if (vg + 1 < VV) op[1] = acc[bi][1] + bq.y;
        if (vg + 2 < VV) op[2] = acc[bi][2] + bq.z;
        if (vg + 3 < VV) op[3] = acc[bi][3] + bq.w;
    }
}

extern "C" void kernel_launch(void* const* d_in, const int* in_sizes, int n_in,
                              void* d_out, int out_size, void* d_ws, size_t ws_size,
                              hipStream_t stream) {
    const float* ihs    = (const float*)d_in[0];
    const int*   tokens = (const int*)  d_in[1];
    const float* emb    = (const float*)d_in[2];
    const float* W      = (const float*)d_in[3];
    const float* U      = (const float*)d_in[4];
    const float* Wout   = (const float*)d_in[5];
    const float* bout   = (const float*)d_in[6];
    float* out = (float*)d_out;

    char* ws = (char*)d_ws;
    float* Ut    = (float*)(ws + 0);          // 360,000 B
    float* hlast = (float*)(ws + 400000);     // 76,800 B
    float* ux    = (float*)(ws + 1048576);    // 39,321,600 B  [T][B][H]

    const int tp_blocks = (H * H + 255) / 256;
    transpose_k<<<tp_blocks, 256, 0, stream>>>(U, Ut);
    ux_k<<<TT, 256, 0, stream>>>(tokens, emb, Ut, ux);
    rnn_k<<<BB, 768, 0, stream>>>(W, ux, ihs, hlast);
    logits_k<<<(VV + 127) / 128, 256, 0, stream>>>(hlast, Wout, bout, out);
}